// Round 7
// baseline (498.658 us; speedup 1.0000x reference)
//
#include <hip/hip_runtime.h>

// out[b,o,n] = max_d |x[b,d,n] - w[o,d]| + bias[o]
// B=64, CIN=1024, COUT=1024, N=49. Pixels P = B*N = 3136 = 49*64.
//
// Round-7: w moved off the scalar path. s_load is OUT-OF-ORDER -> lgkmcnt(0)
// drain before every compute defeated the SGPR double-buffer (rounds 5/6:
// VALUBusy stuck ~58%, idle = exposed SMEM latency). Now: w pre-packed so each
// (wave, k-tile) is 32 contiguous floats; loaded with 8x global_load_dwordx4
// (uniform addr -> HW broadcast) at immediate offsets off one base. Vector
// loads are vmcnt IN-ORDER -> double-buffer genuinely overlaps.
// Inner mix unchanged: v_pk_add_f32(neg) + v_max3(|.|,|.|) = 1.0 instr/update.

typedef float v2f __attribute__((ext_vector_type(2)));
typedef float v4f __attribute__((ext_vector_type(4)));

constexpr int CIN  = 1024;
constexpr int COUT = 1024;
constexpr int NN   = 49;
constexpr int BB   = 64;
constexpr int P    = BB * NN;     // 3136
constexpr int CPW  = 8;           // channels per wave
constexpr int WPB  = 2;           // waves per block (128 threads)
constexpr int CPB  = CPW * WPB;   // 16 channels per block
constexpr int NT   = CIN / 4;     // 256 k-tiles of 4

#define PKSUB(d, wp, xp) \
    asm("v_pk_add_f32 %0, %1, %2 neg_lo:[0,1] neg_hi:[0,1]" \
        : "=v"(d) : "v"(wp), "v"(xp))
#define AMAX3(a, lo, hi) \
    asm("v_max3_f32 %0, %0, |%1|, |%2|" : "+v"(a) : "v"(lo), "v"(hi))

// wq[((og*NT + kt)*8 + c)*4 + ku] = w[og*8+c][kt*4+ku]
__global__ void pack_w_kernel(const float* __restrict__ w, float* __restrict__ wq) {
    int idx = blockIdx.x * 256 + threadIdx.x;     // COUT*CIN / 256 blocks, exact
    int o = idx >> 10, k = idx & 1023;
    int og = o >> 3, c = o & 7, kt = k >> 2, ku = k & 3;
    wq[(((size_t)og * NT + kt) * 8 + c) * 4 + ku] = w[idx];
}

__global__ __launch_bounds__(128) void ndist_kernel(
    const float* __restrict__ x, const float* __restrict__ wq,
    const float* __restrict__ bias, float* __restrict__ out)
{
    const int lane = threadIdx.x & 63;
    const int wid  = __builtin_amdgcn_readfirstlane(threadIdx.x >> 6);

    const int p = blockIdx.y * BB + lane;      // pixel (exact: 3136 = 49*64)
    const int b = p / NN;
    const int n = p - b * NN;
    const int og = blockIdx.x * WPB + wid;     // 8-channel group, 0..127
    const int o0 = og * CPW;

    // opaque lane-zero: keeps the w base formally divergent so the compiler
    // emits vector (broadcast) loads, not out-of-order s_loads
    int lz;
    asm("v_mov_b32 %0, 0" : "=v"(lz));

    const float* __restrict__ xrow = x + (size_t)b * CIN * NN + n;
    const float* __restrict__ wgp  = wq + (size_t)og * (NT * 32) + lz;

    float acc[CPW];
#pragma unroll
    for (int c = 0; c < CPW; ++c) acc[c] = 0.0f;   // |diff| >= 0

    v4f wA[CPW], wB[CPW];    // w quads: [c] = {k0,k1,k2,k3}
    v2f xA[2], xB[2];        // x k-pairs

#define LOAD_X(dst, kt) do {                                   \
        float _x0 = xrow[((kt) * 4 + 0) * NN];                 \
        float _x1 = xrow[((kt) * 4 + 1) * NN];                 \
        float _x2 = xrow[((kt) * 4 + 2) * NN];                 \
        float _x3 = xrow[((kt) * 4 + 3) * NN];                 \
        dst[0] = (v2f){_x0, _x1};                              \
        dst[1] = (v2f){_x2, _x3};                              \
    } while (0)

#define LOAD_W(dst, kt) do {                                   \
        const v4f* _q = (const v4f*)(wgp + (size_t)(kt) * 32); \
        _Pragma("unroll")                                      \
        for (int c = 0; c < CPW; ++c) dst[c] = _q[c];          \
    } while (0)

#define COMPUTE(xv, wv) do {                                   \
        _Pragma("unroll")                                      \
        for (int c = 0; c < CPW; ++c) {                        \
            v2f _lo = __builtin_shufflevector(wv[c], wv[c], 0, 1); \
            v2f _hi = __builtin_shufflevector(wv[c], wv[c], 2, 3); \
            v2f d0, d1;                                        \
            PKSUB(d0, _lo, xv[0]);                             \
            PKSUB(d1, _hi, xv[1]);                             \
            AMAX3(acc[c], d0.x, d0.y);                         \
            AMAX3(acc[c], d1.x, d1.y);                         \
        }                                                      \
    } while (0)

    LOAD_X(xA, 0);
    LOAD_W(wA, 0);

    for (int kt = 0; kt < NT; kt += 2) {
        // prefetch tile kt+1 (vector loads, in-order vmcnt -> true overlap)
        LOAD_X(xB, kt + 1);
        LOAD_W(wB, kt + 1);
        COMPUTE(xA, wA);

        // prefetch tile kt+2 (wrap on last iter; harmless redundant load)
        const int ktn = (kt + 2) & (NT - 1);
        LOAD_X(xA, ktn);
        LOAD_W(wA, ktn);
        COMPUTE(xB, wB);
    }

#pragma unroll
    for (int c = 0; c < CPW; ++c) {
        const int o = o0 + c;
        out[((size_t)b * COUT + o) * NN + n] = acc[c] + bias[o];
    }
}

// ---- fallback (round-6 s_load kernel) if ws can't hold packed w ----
__global__ __launch_bounds__(128) void ndist_fallback(
    const float* __restrict__ x, const float* __restrict__ w,
    const float* __restrict__ bias, float* __restrict__ out)
{
    const int lane = threadIdx.x & 63;
    const int wid  = __builtin_amdgcn_readfirstlane(threadIdx.x >> 6);
    const int p = blockIdx.y * BB + lane;
    const int b = p / NN, n = p - b * NN;
    const int o0 = blockIdx.x * CPB + wid * CPW;
    const float* __restrict__ xrow = x + (size_t)b * CIN * NN + n;
    const float* __restrict__ wb   = w + (size_t)o0 * CIN;

    float acc[CPW];
#pragma unroll
    for (int c = 0; c < CPW; ++c) acc[c] = 0.0f;

    for (int kt = 0; kt < NT; ++kt) {
        v2f xv[2];
        LOAD_X(xv, kt);
#pragma unroll
        for (int c = 0; c < CPW; ++c) {
            v4f t = *(const v4f*)(wb + (size_t)c * CIN + kt * 4);
            v2f lo = __builtin_shufflevector(t, t, 0, 1);
            v2f hi = __builtin_shufflevector(t, t, 2, 3);
            v2f d0, d1;
            PKSUB(d0, lo, xv[0]);
            PKSUB(d1, hi, xv[1]);
            AMAX3(acc[c], d0.x, d0.y);
            AMAX3(acc[c], d1.x, d1.y);
        }
    }
#pragma unroll
    for (int c = 0; c < CPW; ++c) {
        const int o = o0 + c;
        out[((size_t)b * COUT + o) * NN + n] = acc[c] + bias[o];
    }
}

extern "C" void kernel_launch(void* const* d_in, const int* in_sizes, int n_in,
                              void* d_out, int out_size, void* d_ws, size_t ws_size,
                              hipStream_t stream) {
    const float* x    = (const float*)d_in[0];
    const float* w    = (const float*)d_in[1];
    const float* bias = (const float*)d_in[2];
    float* out        = (float*)d_out;

    const size_t wq_bytes = (size_t)COUT * CIN * sizeof(float);  // 4 MB
    dim3 grid(COUT / CPB, P / BB);   // (64 channel-groups, 49 pixel-tiles)
    if (ws_size >= wq_bytes) {
        float* wqd = (float*)d_ws;
        pack_w_kernel<<<(COUT * CIN) / 256, 256, 0, stream>>>(w, wqd);
        ndist_kernel<<<grid, 128, 0, stream>>>(x, wqd, bias, out);
    } else {
        ndist_fallback<<<grid, 128, 0, stream>>>(x, w, bias, out);
    }
}

// Round 8
// 153.963 us; speedup vs baseline: 3.2388x; 3.2388x over previous
//
#include <hip/hip_runtime.h>

// out[b,o,n] = max_d |x[b,d,n] - w[o,d]| + bias[o]
// B=64, CIN=1024, COUT=1024, N=49. Pixels P = B*N = 3136 = 49*64.
//
// Round-8: w distribution via LDS broadcast.
//  - round 5/6: s_load double-buffer dead (SMEM returns OOO -> lgkmcnt(0) drain)
//  - round 7: uniform VMEM loads replicate 16B/lane on the return path (64x) -> 499us
//  - now: w staged into LDS in K-chunks of 64 (8KB double-buffered), read with
//    wave-uniform ds_read_b128 = hardware broadcast (no conflict, counted lgkmcnt
//    -> per-tile register double-buffer genuinely overlaps).
//  - staging is reg-staged + async-split: global_load_dwordx4 issued BEFORE the
//    chunk's compute, ds_write AFTER it (T14), one barrier per chunk.
// Inner mix unchanged: v_pk_add_f32(neg) + v_max3(|.|,|.|) per (ch, k-pair).

typedef float v2f __attribute__((ext_vector_type(2)));
typedef float v4f __attribute__((ext_vector_type(4)));

constexpr int CIN  = 1024;
constexpr int COUT = 1024;
constexpr int NN   = 49;
constexpr int BB   = 64;
constexpr int P    = BB * NN;     // 3136
constexpr int CPW  = 8;           // channels per wave
constexpr int WPB  = 2;           // waves per block (128 threads)
constexpr int CPB  = CPW * WPB;   // 16 channels per block
constexpr int KC   = 64;          // k per LDS chunk
constexpr int NCH  = CIN / KC;    // 16 chunks
constexpr int TPC  = KC / 4;      // 16 k-tiles per chunk
constexpr int NTL  = CIN / 4;     // 256 k-tiles total

#define PKSUB(d, wp, xp) \
    asm("v_pk_add_f32 %0, %1, %2 neg_lo:[0,1] neg_hi:[0,1]" \
        : "=v"(d) : "v"(wp), "v"(xp))
#define AMAX3(a, lo, hi) \
    asm("v_max3_f32 %0, %0, |%1|, |%2|" : "+v"(a) : "v"(lo), "v"(hi))

__global__ __launch_bounds__(128) void ndist_kernel(
    const float* __restrict__ x, const float* __restrict__ w,
    const float* __restrict__ bias, float* __restrict__ out)
{
    __shared__ float ws[2][CPB * KC];   // 2 x 4 KB

    const int t    = threadIdx.x;
    const int lane = t & 63;
    const int wid  = __builtin_amdgcn_readfirstlane(t >> 6);

    const int p = blockIdx.y * BB + lane;    // pixel (exact: 3136 = 49*64)
    const int b = p / NN;
    const int n = p - b * NN;
    const int o0b = blockIdx.x * CPB;        // block channel base
    const int o0  = o0b + wid * CPW;         // wave channel base

    const float* __restrict__ xrow = x + (size_t)b * CIN * NN + n;

    // --- staging addresses: thread t covers LDS elements [4t..4t+4) and
    // [512+4t..512+4t+4) of the 1024-float chunk buffer; element e -> c=e/64,
    // k=e%64. Global: w[(o0b+c)*CIN + ch*64 + k]. Coalesced 256B per channel row.
    const int sc = t >> 4;                   // 0..7
    const int sk = (t & 15) * 4;
    const float* __restrict__ g0 = w + (size_t)(o0b + sc) * CIN + sk;       // c = sc
    const float* __restrict__ g1 = g0 + (size_t)8 * CIN;                    // c = sc+8
    const int e0 = t * 4;

    float acc[CPW];
#pragma unroll
    for (int c = 0; c < CPW; ++c) acc[c] = 0.0f;   // |diff| >= 0

    v2f xA[2], xB[2];            // x k-pairs (per-lane)
    v2f wA[CPW][2], wB[CPW][2];  // w k-pairs (broadcast from LDS)

#define LOAD_X(dst, kt) do {                                   \
        float _x0 = xrow[((kt) * 4 + 0) * NN];                 \
        float _x1 = xrow[((kt) * 4 + 1) * NN];                 \
        float _x2 = xrow[((kt) * 4 + 2) * NN];                 \
        float _x3 = xrow[((kt) * 4 + 3) * NN];                 \
        dst[0] = (v2f){_x0, _x1};                              \
        dst[1] = (v2f){_x2, _x3};                              \
    } while (0)

    // wave-uniform address -> ds_read_b128 broadcast, counted lgkmcnt
#define LOAD_WS(dst, wsb, j) do {                              \
        _Pragma("unroll")                                      \
        for (int c = 0; c < CPW; ++c) {                        \
            v4f q = *(const v4f*)((wsb) + c * KC + (j) * 4);   \
            dst[c][0] = __builtin_shufflevector(q, q, 0, 1);   \
            dst[c][1] = __builtin_shufflevector(q, q, 2, 3);   \
        }                                                      \
    } while (0)

#define COMPUTE(xv, wv) do {                                   \
        _Pragma("unroll")                                      \
        for (int c = 0; c < CPW; ++c) {                        \
            v2f d0, d1;                                        \
            PKSUB(d0, wv[c][0], xv[0]);                        \
            PKSUB(d1, wv[c][1], xv[1]);                        \
            AMAX3(acc[c], d0.x, d0.y);                         \
            AMAX3(acc[c], d1.x, d1.y);                         \
        }                                                      \
    } while (0)

    // --- prologue: stage chunk 0, first x tile ---
    {
        v4f r0 = *(const v4f*)g0;
        v4f r1 = *(const v4f*)g1;
        *(v4f*)&ws[0][e0]       = r0;
        *(v4f*)&ws[0][e0 + 512] = r1;
    }
    __syncthreads();
    LOAD_X(xA, 0);

    for (int ch = 0; ch < NCH; ++ch) {
        const int buf = ch & 1;
        const bool more = (ch + 1 < NCH);

        // issue next chunk's global loads early (latency hides under compute)
        v4f p0, p1;
        if (more) {
            p0 = *(const v4f*)(g0 + (ch + 1) * KC);
            p1 = *(const v4f*)(g1 + (ch + 1) * KC);
        }

        const float* __restrict__ wsb = &ws[buf][wid * (CPW * KC)];
        LOAD_WS(wA, wsb, 0);
#pragma unroll
        for (int j = 0; j < TPC; j += 2) {
            const int tg = ch * TPC + j;
            LOAD_X(xB, tg + 1);
            LOAD_WS(wB, wsb, j + 1);
            COMPUTE(xA, wA);
            const int tn = (tg + 2) & (NTL - 1);        // wrap at very end: harmless
            LOAD_X(xA, tn);
            LOAD_WS(wA, wsb, (j + 2) & (TPC - 1));      // wrap within chunk: harmless
            COMPUTE(xB, wB);
        }

        // write prefetched chunk into the other buffer (safe: that buffer was
        // fully consumed before the barrier that ended the previous iteration)
        if (more) {
            float* d = &ws[buf ^ 1][0];
            *(v4f*)&d[e0]       = p0;
            *(v4f*)&d[e0 + 512] = p1;
        }
        __syncthreads();
    }

#pragma unroll
    for (int c = 0; c < CPW; ++c) {
        const int o = o0 + c;
        out[((size_t)b * COUT + o) * NN + n] = acc[c] + bias[o];
    }
}

extern "C" void kernel_launch(void* const* d_in, const int* in_sizes, int n_in,
                              void* d_out, int out_size, void* d_ws, size_t ws_size,
                              hipStream_t stream) {
    const float* x    = (const float*)d_in[0];
    const float* w    = (const float*)d_in[1];
    const float* bias = (const float*)d_in[2];
    float* out        = (float*)d_out;

    dim3 grid(COUT / CPB, P / BB);   // (64 channel-groups, 49 pixel-tiles) = 3136 blocks
    ndist_kernel<<<grid, 128, 0, stream>>>(x, w, bias, out);
}